// Round 2
// baseline (1813.208 us; speedup 1.0000x reference)
//
#include <hip/hip_runtime.h>
#include <hip/hip_bf16.h>
#include <float.h>

#define B_ 4
#define N_ 1024
#define DIM_ 1024
#define H_ 16
#define DH_ 64
#define NM_ 4
#define J_ 1028          // N_ + NM_
#define TOPK_ 64
#define QKSCALE 10.0f

typedef __attribute__((ext_vector_type(8))) short short8;
typedef __attribute__((ext_vector_type(4))) float f32x4;
typedef __attribute__((ext_vector_type(8))) unsigned short ushort8;
typedef __attribute__((ext_vector_type(4))) unsigned short ushort4v;
typedef __attribute__((ext_vector_type(4))) unsigned int u32x4;

__device__ __forceinline__ float b2f(unsigned short u){
  union { unsigned int i; float f; } c; c.i = ((unsigned int)u) << 16; return c.f;
}
__device__ __forceinline__ unsigned short f2b(float f){
  union { float f; unsigned int i; } c; c.f = f;
  unsigned int r = c.i + 0x7FFFu + ((c.i >> 16) & 1u);   // RNE
  return (unsigned short)(r >> 16);
}
__device__ __forceinline__ float lo16(unsigned int u){ return __uint_as_float(u << 16); }
__device__ __forceinline__ float hi16(unsigned int u){ return __uint_as_float(u & 0xFFFF0000u); }

// ---------------- f32 -> bf16 convert (grid-stride) ----------------
__global__ void k_cvt(const float* __restrict__ s, unsigned short* __restrict__ d, int n){
  int i = blockIdx.x * 256 + threadIdx.x;
  int st = gridDim.x * 256;
  for (; i < n; i += st) d[i] = f2b(s[i]);
}

// ---------------- memory-slot prep: normalize mem_k, copy mem_v ----------------
__global__ __launch_bounds__(256) void k_mem(const float* __restrict__ mk, const float* __restrict__ mv,
                                             unsigned short* __restrict__ kn, unsigned short* __restrict__ vc){
  int wid = blockIdx.x * 4 + (threadIdx.x >> 6);   // 0..63
  int lane = threadIdx.x & 63;
  int h = wid >> 2, mm = wid & 3;
  float kv = mk[(h * NM_ + mm) * DH_ + lane];
  float ss = kv * kv;
  #pragma unroll
  for (int off = 32; off; off >>= 1) ss += __shfl_xor(ss, off);
  float rn = 1.f / fmaxf(sqrtf(ss), 1e-12f);
  unsigned short kb = f2b(kv * rn);
  unsigned short vb = f2b(mv[(h * NM_ + mm) * DH_ + lane]);
  for (int b = 0; b < B_; ++b){
    int base = ((b * H_ + h) * J_ + mm) * DH_ + lane;
    kn[base] = kb;
    vc[base] = vb;
  }
}

// ---------------- transpose kn [bg][j][d] -> ktp [bg][dp][j] (bf16 pairs as u32) ----------------
__global__ __launch_bounds__(256) void k_tr(const unsigned short* __restrict__ kn,
                                            unsigned int* __restrict__ ktp){
  __shared__ unsigned int tile[64][33];
  const int bg = blockIdx.y;           // b*16+g
  const int jb = blockIdx.x * 64;      // j tile base (17 tiles)
  const int t = threadIdx.x;
  const unsigned int* src = (const unsigned int*)(kn + (size_t)bg * J_ * DH_);  // 32 u32 per j-row
  #pragma unroll
  for (int p = 0; p < 2; ++p){
    int c = t + p * 256;               // 0..511
    int row = c >> 3, c4 = (c & 7) * 4;
    int j = jb + row;
    if (j < J_){
      u32x4 v = *(const u32x4*)(src + (size_t)j * 32 + c4);
      tile[row][c4 + 0] = v[0]; tile[row][c4 + 1] = v[1];
      tile[row][c4 + 2] = v[2]; tile[row][c4 + 3] = v[3];
    }
  }
  __syncthreads();
  #pragma unroll
  for (int p = 0; p < 2; ++p){
    int c = t + p * 256;               // 0..511
    int dp = c >> 4, j4 = (c & 15) * 4;
    int j = jb + j4;
    if (j + 3 < J_){
      u32x4 w;
      w[0] = tile[j4 + 0][dp]; w[1] = tile[j4 + 1][dp];
      w[2] = tile[j4 + 2][dp]; w[3] = tile[j4 + 3][dp];
      *(u32x4*)(ktp + ((size_t)bg * 32 + dp) * J_ + j) = w;
    }
  }
}

// ---------------- bf16 MFMA GEMM 4096x1024x1024, 128x128 tile, 4 waves ----------------
// MODE 0: v -> vc ; MODE 1: q -> qn (l2norm*scale) ; MODE 2: k -> kn (l2norm)
// MODE 3: gate -> sigmoid(P+bg) bf16 ; MODE 4: f32 out
template<int MODE>
__global__ __launch_bounds__(256) void k_gemm(const unsigned short* __restrict__ A,
                                              const unsigned short* __restrict__ W,
                                              void* __restrict__ outp,
                                              const float* __restrict__ bg)
{
  __shared__ unsigned short As[128][40];
  __shared__ unsigned short Bs[128][40];
  const int t = threadIdx.x;
  const int m0 = blockIdx.y * 128, n0 = blockIdx.x * 128;
  const int l = t & 63, w = t >> 6, wr = w >> 1, wc = w & 1;

  f32x4 acc[4][4];
  #pragma unroll
  for (int a = 0; a < 4; ++a)
    #pragma unroll
    for (int b2 = 0; b2 < 4; ++b2) acc[a][b2] = (f32x4){0.f, 0.f, 0.f, 0.f};

  for (int k0 = 0; k0 < 1024; k0 += 32){
    #pragma unroll
    for (int cc = 0; cc < 2; ++cc){
      int c = t + cc * 256;
      int row = c >> 2, colc = (c & 3) * 8;
      *(ushort8*)&As[row][colc] = *(const ushort8*)&A[(m0 + row) * 1024 + k0 + colc];
    }
    #pragma unroll
    for (int cc = 0; cc < 2; ++cc){
      int c = t + cc * 256;
      int kk = c >> 4, nc = (c & 15) * 8;
      ushort8 vb = *(const ushort8*)&W[(k0 + kk) * 1024 + n0 + nc];
      #pragma unroll
      for (int e = 0; e < 8; ++e) Bs[nc + e][kk] = vb[e];
    }
    __syncthreads();
    short8 af[4], bfr[4];
    #pragma unroll
    for (int mf = 0; mf < 4; ++mf) af[mf]  = *(const short8*)&As[wr * 64 + mf * 16 + (l & 15)][(l >> 4) * 8];
    #pragma unroll
    for (int nf = 0; nf < 4; ++nf) bfr[nf] = *(const short8*)&Bs[wc * 64 + nf * 16 + (l & 15)][(l >> 4) * 8];
    #pragma unroll
    for (int mf = 0; mf < 4; ++mf)
      #pragma unroll
      for (int nf = 0; nf < 4; ++nf)
        acc[mf][nf] = __builtin_amdgcn_mfma_f32_16x16x32_bf16(af[mf], bfr[nf], acc[mf][nf], 0, 0, 0);
    __syncthreads();
  }

  int hcol = (n0 + wc * 64) >> 6;
  #pragma unroll
  for (int mf = 0; mf < 4; ++mf){
    #pragma unroll
    for (int r = 0; r < 4; ++r){
      int row = m0 + wr * 64 + mf * 16 + (l >> 4) * 4 + r;
      float rn = 1.f;
      if (MODE == 1 || MODE == 2){
        float ss = 0.f;
        #pragma unroll
        for (int nf = 0; nf < 4; ++nf) ss += acc[mf][nf][r] * acc[mf][nf][r];
        #pragma unroll
        for (int off = 1; off < 16; off <<= 1) ss += __shfl_xor(ss, off);
        rn = 1.f / fmaxf(sqrtf(ss), 1e-12f);
        if (MODE == 1) rn *= QKSCALE;
      }
      #pragma unroll
      for (int nf = 0; nf < 4; ++nf){
        int col = n0 + wc * 64 + nf * 16 + (l & 15);
        float v = acc[mf][nf][r];
        if (MODE == 4){
          ((float*)outp)[row * 1024 + col] = v;
        } else if (MODE == 3){
          float g = v + bg[col];
          ((unsigned short*)outp)[row * 1024 + col] = f2b(1.f / (1.f + __expf(-g)));
        } else {
          int bb = row >> 10, ii = row & 1023;
          int d = nf * 16 + (l & 15);
          if (MODE == 1)
            ((unsigned short*)outp)[((bb * H_ + hcol) * N_ + ii) * DH_ + d] = f2b(v * rn);
          else
            ((unsigned short*)outp)[((bb * H_ + hcol) * J_ + NM_ + ii) * DH_ + d] = f2b(v * rn);
        }
      }
    }
  }
}

// ---------------- fused attention: one workgroup per (b, i), big rows first ----------------
__global__ __launch_bounds__(256) void k_attn(
  const unsigned short* __restrict__ qn, const unsigned int* __restrict__ ktp,
  const unsigned short* __restrict__ vc, const float* __restrict__ wpre,
  const float* __restrict__ wpost, const float* __restrict__ hsc,
  const unsigned short* __restrict__ gate, unsigned short* __restrict__ aout)
{
  __shared__ float sd[16][J_];     // raw dots -> mixed -> attn (in place)

  const int blk = blockIdx.x;
  const int b = blk & 3;
  const int i = 1023 - (blk >> 2);       // big rows dispatched first
  const int nA = i + 5;                  // 4 memory slots + causal (j <= i+4)
  const int t = threadIdx.x;
  const unsigned int* qb = (const unsigned int*)qn;

  // ---- raw dots: thread = column j (coalesced ktp reads), q via uniform scalar loads ----
  for (int jb = 0; jb < nA; jb += 256){
    int j = jb + t;
    if (j < nA){
      for (int g = 0; g < 16; ++g){
        const unsigned int* qrow = qb + ((size_t)(b * H_ + g) * N_ + i) * 32;  // 32 bf16-pairs (uniform)
        const unsigned int* kk = ktp + ((size_t)(b * H_ + g) * 32) * J_ + j;
        float a = 0.f;
        #pragma unroll
        for (int dp = 0; dp < 32; ++dp){
          unsigned int uq = qrow[dp];          // wave-uniform -> s_load
          unsigned int uk = kk[(size_t)dp * J_];
          a += lo16(uq) * lo16(uk);
          a += hi16(uq) * hi16(uk);
        }
        sd[g][j] = a;
      }
    }
  }
  __syncthreads();

  // ---- W_pre mix, per column (in place, column-exclusive) ----
  for (int j = t; j < nA; j += 256){
    float a[16];
    #pragma unroll
    for (int g = 0; g < 16; ++g) a[g] = sd[g][j];
    #pragma unroll
    for (int h = 0; h < 16; ++h){
      float m = 0.f;
      #pragma unroll
      for (int g = 0; g < 16; ++g) m += wpre[h * 16 + g] * a[g];   // uniform scalar loads
      sd[h][j] = m;
    }
  }
  __syncthreads();

  // ---- per-head top-64 threshold + softmax (one wave per head-row) ----
  const int w = t >> 6, lane = t & 63;
  for (int h = w; h < 16; h += 4){
    float v[17]; unsigned int key[17];
    #pragma unroll
    for (int r = 0; r < 17; ++r){
      int j = lane + 64 * r;
      float x = (j < nA) ? sd[h][j] : -FLT_MAX;
      v[r] = x;
      unsigned int u = __float_as_uint(x);
      key[r] = (u >> 31) ? ~u : (u | 0x80000000u);   // monotone order-preserving map
    }
    float mx = v[0];
    #pragma unroll
    for (int r = 1; r < 17; ++r) mx = fmaxf(mx, v[r]);
    #pragma unroll
    for (int off = 32; off; off >>= 1) mx = fmaxf(mx, __shfl_xor(mx, off));

    unsigned int T = 0u;
    if (nA > TOPK_){
      for (int bit = 31; bit >= 8; --bit){     // 24-bit greedy search for 64th-largest key
        unsigned int Tc = T | (1u << bit);
        int c = 0;
        #pragma unroll
        for (int r = 0; r < 17; ++r)
          c += __popcll(__ballot(key[r] >= Tc));   // SALU popcount, no shuffle chain
        if (c >= TOPK_) T = Tc;
      }
    }
    float s = 0.f;
    #pragma unroll
    for (int r = 0; r < 17; ++r){
      int j = lane + 64 * r;
      float e = (j < nA && key[r] >= T) ? __expf(v[r] - mx) : 0.f;
      v[r] = e; s += e;
    }
    #pragma unroll
    for (int off = 32; off; off >>= 1) s += __shfl_xor(s, off);
    float inv = 1.f / s;
    #pragma unroll
    for (int r = 0; r < 17; ++r){
      int j = lane + 64 * r;
      if (j < J_) sd[h][j] = v[r] * inv;
    }
  }
  __syncthreads();

  // ---- W_post mix, per column (in place) ----
  for (int j = t; j < nA; j += 256){
    float a[16];
    #pragma unroll
    for (int g = 0; g < 16; ++g) a[g] = sd[g][j];
    #pragma unroll
    for (int h = 0; h < 16; ++h){
      float m = 0.f;
      #pragma unroll
      for (int g = 0; g < 16; ++g) m += wpost[h * 16 + g] * a[g];
      sd[h][j] = m;
    }
  }
  __syncthreads();

  // ---- PV + head_scale + gate: thread (h, sg) does 4 d's ----
  const int h = t >> 4, sg = t & 15, d0 = sg * 4;
  const unsigned short* vbase = vc + ((size_t)(b * H_ + h) * J_) * DH_ + d0;
  float acc[4] = {0.f, 0.f, 0.f, 0.f};
  const int nA4 = nA & ~3;
  for (int j4 = 0; j4 < nA4; j4 += 4){
    f32x4 aa = *(const f32x4*)&sd[h][j4];
    #pragma unroll
    for (int e = 0; e < 4; ++e){
      float a = aa[e];
      ushort4v vv = *(const ushort4v*)(vbase + (size_t)(j4 + e) * DH_);
      acc[0] += a * b2f(vv[0]);
      acc[1] += a * b2f(vv[1]);
      acc[2] += a * b2f(vv[2]);
      acc[3] += a * b2f(vv[3]);
    }
  }
  for (int j = nA4; j < nA; ++j){
    float a = sd[h][j];
    ushort4v vv = *(const ushort4v*)(vbase + (size_t)j * DH_);
    acc[0] += a * b2f(vv[0]);
    acc[1] += a * b2f(vv[1]);
    acc[2] += a * b2f(vv[2]);
    acc[3] += a * b2f(vv[3]);
  }
  float hs = hsc[h];
  const int row = (b << 10) | i;
  #pragma unroll
  for (int r = 0; r < 4; ++r){
    float g = b2f(gate[(size_t)row * 1024 + h * 64 + d0 + r]);
    aout[(size_t)row * 1024 + h * 64 + d0 + r] = f2b(acc[r] * hs * g);
  }
}

// ---------------- host ----------------
extern "C" void kernel_launch(void* const* d_in, const int* in_sizes, int n_in,
                              void* d_out, int out_size, void* d_ws, size_t ws_size,
                              hipStream_t stream) {
  const float* x     = (const float*)d_in[0];
  const float* Wq    = (const float*)d_in[1];
  const float* Wk    = (const float*)d_in[2];
  const float* Wv    = (const float*)d_in[3];
  const float* Wpre  = (const float*)d_in[4];
  const float* Wpost = (const float*)d_in[5];
  const float* mk    = (const float*)d_in[6];
  const float* mv    = (const float*)d_in[7];
  const float* hsc   = (const float*)d_in[8];
  const float* Wg    = (const float*)d_in[9];
  const float* bg    = (const float*)d_in[10];
  const float* Wo    = (const float*)d_in[11];
  float* out = (float*)d_out;

  char* ws = (char*)d_ws;
  size_t off = 0;
  auto alloc = [&](size_t bytes) -> void* {
    void* p = ws + off; off += (bytes + 255) & ~(size_t)255; return p;
  };
  unsigned short* xb   = (unsigned short*)alloc((size_t)4096 * 1024 * 2);
  unsigned short* wqb  = (unsigned short*)alloc((size_t)1024 * 1024 * 2);
  unsigned short* wkb  = (unsigned short*)alloc((size_t)1024 * 1024 * 2);
  unsigned short* wvb  = (unsigned short*)alloc((size_t)1024 * 1024 * 2);
  unsigned short* wgb  = (unsigned short*)alloc((size_t)1024 * 1024 * 2);
  unsigned short* wob  = (unsigned short*)alloc((size_t)1024 * 1024 * 2);
  unsigned short* qn   = (unsigned short*)alloc((size_t)B_ * H_ * N_ * DH_ * 2);
  unsigned short* kn   = (unsigned short*)alloc((size_t)B_ * H_ * J_ * DH_ * 2);
  unsigned short* vc   = (unsigned short*)alloc((size_t)B_ * H_ * J_ * DH_ * 2);
  unsigned short* gate = (unsigned short*)alloc((size_t)4096 * 1024 * 2);
  unsigned short* aout = (unsigned short*)alloc((size_t)4096 * 1024 * 2);
  unsigned int*   ktp  = (unsigned int*)alloc((size_t)B_ * H_ * 32 * J_ * 4);

  k_cvt<<<1024, 256, 0, stream>>>(x,  xb,  4096 * 1024);
  k_cvt<<<512,  256, 0, stream>>>(Wq, wqb, 1024 * 1024);
  k_cvt<<<512,  256, 0, stream>>>(Wk, wkb, 1024 * 1024);
  k_cvt<<<512,  256, 0, stream>>>(Wv, wvb, 1024 * 1024);
  k_cvt<<<512,  256, 0, stream>>>(Wg, wgb, 1024 * 1024);
  k_cvt<<<512,  256, 0, stream>>>(Wo, wob, 1024 * 1024);

  k_mem<<<16, 256, 0, stream>>>(mk, mv, kn, vc);

  dim3 gg(8, 32);
  k_gemm<0><<<gg, 256, 0, stream>>>(xb, wvb, vc,   nullptr);
  k_gemm<1><<<gg, 256, 0, stream>>>(xb, wqb, qn,   nullptr);
  k_gemm<2><<<gg, 256, 0, stream>>>(xb, wkb, kn,   nullptr);
  k_gemm<3><<<gg, 256, 0, stream>>>(xb, wgb, gate, bg);

  k_tr<<<dim3(17, B_ * H_), 256, 0, stream>>>(kn, ktp);

  k_attn<<<4096, 256, 0, stream>>>(qn, ktp, vc, Wpre, Wpost, hsc, gate, aout);

  k_gemm<4><<<gg, 256, 0, stream>>>(aout, wob, out, nullptr);
}

// Round 3
// 639.266 us; speedup vs baseline: 2.8364x; 2.8364x over previous
//
#include <hip/hip_runtime.h>
#include <hip/hip_bf16.h>
#include <float.h>

#define B_ 4
#define N_ 1024
#define DIM_ 1024
#define H_ 16
#define DH_ 64
#define NM_ 4
#define J_ 1028          // N_ + NM_
#define JP_ 514          // J_/2 pairs
#define JB_ 33           // ceil(J_/32) j-blocks
#define TOPK_ 64
#define QKSCALE 10.0f

typedef __attribute__((ext_vector_type(8))) short short8;
typedef __attribute__((ext_vector_type(4))) float f32x4;
typedef __attribute__((ext_vector_type(8))) unsigned short ushort8;
typedef __attribute__((ext_vector_type(4))) unsigned int u32x4;
typedef _Float16 half2v __attribute__((ext_vector_type(2)));

__device__ __forceinline__ unsigned short f2b(float f){
  union { float f; unsigned int i; } c; c.f = f;
  unsigned int r = c.i + 0x7FFFu + ((c.i >> 16) & 1u);   // RNE
  return (unsigned short)(r >> 16);
}
__device__ __forceinline__ unsigned short f2h(float f){
  return __builtin_bit_cast(unsigned short, (_Float16)f);
}
__device__ __forceinline__ float h2f(unsigned short u){
  return (float)__builtin_bit_cast(_Float16, u);
}
__device__ __forceinline__ float fdot2(unsigned int a, unsigned int b, float c){
  return __builtin_amdgcn_fdot2(__builtin_bit_cast(half2v, a),
                                __builtin_bit_cast(half2v, b), c, false);
}

// ---------------- f32 -> bf16 convert (grid-stride) ----------------
__global__ void k_cvt(const float* __restrict__ s, unsigned short* __restrict__ d, int n){
  int i = blockIdx.x * 256 + threadIdx.x;
  int st = gridDim.x * 256;
  for (; i < n; i += st) d[i] = f2b(s[i]);
}

// ---------------- memory-slot prep: normalize mem_k (f16), pack mem_v pairs ----------------
__global__ __launch_bounds__(256) void k_mem(const float* __restrict__ mk, const float* __restrict__ mv,
                                             unsigned short* __restrict__ kn, unsigned int* __restrict__ vp){
  int h = blockIdx.x * 4 + (threadIdx.x >> 6);   // 0..15
  int d = threadIdx.x & 63;
  unsigned short kh[4]; float vv[4];
  #pragma unroll
  for (int mm = 0; mm < 4; ++mm){
    float kv = mk[(h * 4 + mm) * 64 + d];
    float ss = kv * kv;
    #pragma unroll
    for (int off = 32; off; off >>= 1) ss += __shfl_xor(ss, off);
    kh[mm] = f2h(kv / fmaxf(sqrtf(ss), 1e-12f));
    vv[mm] = mv[(h * 4 + mm) * 64 + d];
  }
  unsigned int p01 = (unsigned int)f2h(vv[0]) | ((unsigned int)f2h(vv[1]) << 16);
  unsigned int p23 = (unsigned int)f2h(vv[2]) | ((unsigned int)f2h(vv[3]) << 16);
  for (int b = 0; b < B_; ++b){
    int bg = b * 16 + h;
    #pragma unroll
    for (int mm = 0; mm < 4; ++mm) kn[((size_t)bg * J_ + mm) * 64 + d] = kh[mm];
    vp[((size_t)bg * JP_ + 0) * 64 + d] = p01;
    vp[((size_t)bg * JP_ + 1) * 64 + d] = p23;
  }
}

// ---------------- K re-tile: kn [bg][j][d] f16 -> ktp [bg][j/32][dp][j%32] u32 pairs ----------------
__global__ __launch_bounds__(256) void k_tr(const unsigned short* __restrict__ kn,
                                            unsigned int* __restrict__ ktp){
  __shared__ unsigned int tile[32][33];
  const int bg = blockIdx.y;
  const int jb = blockIdx.x;           // 0..32
  const int t = threadIdx.x;
  const unsigned int* src = (const unsigned int*)kn + (size_t)bg * J_ * 32;
  {
    int rr = t >> 3, cc = (t & 7) * 4;         // row 0..31, col-chunk
    int j = jb * 32 + rr;
    u32x4 v = {0u, 0u, 0u, 0u};
    if (j < J_) v = *(const u32x4*)(src + (size_t)j * 32 + cc);
    tile[rr][cc + 0] = v[0]; tile[rr][cc + 1] = v[1];
    tile[rr][cc + 2] = v[2]; tile[rr][cc + 3] = v[3];
  }
  __syncthreads();
  {
    int dp = t >> 3, jc = (t & 7) * 4;
    u32x4 w;
    #pragma unroll
    for (int e = 0; e < 4; ++e) w[e] = tile[jc + e][dp];
    *(u32x4*)(ktp + (((size_t)bg * JB_ + jb) * 32 + dp) * 32 + jc) = w;
  }
}

// ---------------- bf16 MFMA GEMM 4096x1024x1024, 128x128 tile, 4 waves ----------------
// MODE 0: v -> vp (f16 j-pair-packed u32 [bg][jp][d])
// MODE 1: q -> qn f16 (l2norm*QKSCALE) ; MODE 2: k -> kn f16 (l2norm)
// MODE 3: gate -> sigmoid(P+bg) f16 ; MODE 4: f32 out
template<int MODE>
__global__ __launch_bounds__(256) void k_gemm(const unsigned short* __restrict__ A,
                                              const unsigned short* __restrict__ W,
                                              void* __restrict__ outp,
                                              const float* __restrict__ bg)
{
  __shared__ unsigned short As[128][40];
  __shared__ unsigned short Bs[128][40];
  const int t = threadIdx.x;
  const int m0 = blockIdx.y * 128, n0 = blockIdx.x * 128;
  const int l = t & 63, w = t >> 6, wr = w >> 1, wc = w & 1;

  f32x4 acc[4][4];
  #pragma unroll
  for (int a = 0; a < 4; ++a)
    #pragma unroll
    for (int b2 = 0; b2 < 4; ++b2) acc[a][b2] = (f32x4){0.f, 0.f, 0.f, 0.f};

  for (int k0 = 0; k0 < 1024; k0 += 32){
    #pragma unroll
    for (int cc = 0; cc < 2; ++cc){
      int c = t + cc * 256;
      int row = c >> 2, colc = (c & 3) * 8;
      *(ushort8*)&As[row][colc] = *(const ushort8*)&A[(m0 + row) * 1024 + k0 + colc];
    }
    #pragma unroll
    for (int cc = 0; cc < 2; ++cc){
      int c = t + cc * 256;
      int kk = c >> 4, nc = (c & 15) * 8;
      ushort8 vb = *(const ushort8*)&W[(k0 + kk) * 1024 + n0 + nc];
      #pragma unroll
      for (int e = 0; e < 8; ++e) Bs[nc + e][kk] = vb[e];
    }
    __syncthreads();
    short8 af[4], bfr[4];
    #pragma unroll
    for (int mf = 0; mf < 4; ++mf) af[mf]  = *(const short8*)&As[wr * 64 + mf * 16 + (l & 15)][(l >> 4) * 8];
    #pragma unroll
    for (int nf = 0; nf < 4; ++nf) bfr[nf] = *(const short8*)&Bs[wc * 64 + nf * 16 + (l & 15)][(l >> 4) * 8];
    #pragma unroll
    for (int mf = 0; mf < 4; ++mf)
      #pragma unroll
      for (int nf = 0; nf < 4; ++nf)
        acc[mf][nf] = __builtin_amdgcn_mfma_f32_16x16x32_bf16(af[mf], bfr[nf], acc[mf][nf], 0, 0, 0);
    __syncthreads();
  }

  if constexpr (MODE == 0){
    // pairs over consecutive rows (j): r0/r1 -> jp0, r2/r3 -> jp0+1
    #pragma unroll
    for (int mf = 0; mf < 4; ++mf){
      int row0 = m0 + wr * 64 + mf * 16 + (l >> 4) * 4;
      int bb = row0 >> 10, ii0 = row0 & 1023;
      int jp0 = (ii0 + NM_) >> 1;
      #pragma unroll
      for (int nf = 0; nf < 4; ++nf){
        int col = n0 + wc * 64 + nf * 16 + (l & 15);
        int h = col >> 6, d = col & 63;
        unsigned int p01 = (unsigned int)f2h(acc[mf][nf][0]) | ((unsigned int)f2h(acc[mf][nf][1]) << 16);
        unsigned int p23 = (unsigned int)f2h(acc[mf][nf][2]) | ((unsigned int)f2h(acc[mf][nf][3]) << 16);
        unsigned int* vpb = (unsigned int*)outp + ((size_t)(bb * 16 + h) * JP_ + jp0) * 64 + d;
        vpb[0]  = p01;
        vpb[64] = p23;
      }
    }
  } else {
    int hcol = (n0 + wc * 64) >> 6;
    #pragma unroll
    for (int mf = 0; mf < 4; ++mf){
      #pragma unroll
      for (int r = 0; r < 4; ++r){
        int row = m0 + wr * 64 + mf * 16 + (l >> 4) * 4 + r;
        float rn = 1.f;
        if (MODE == 1 || MODE == 2){
          float ss = 0.f;
          #pragma unroll
          for (int nf = 0; nf < 4; ++nf) ss += acc[mf][nf][r] * acc[mf][nf][r];
          #pragma unroll
          for (int off = 1; off < 16; off <<= 1) ss += __shfl_xor(ss, off);
          rn = 1.f / fmaxf(sqrtf(ss), 1e-12f);
          if (MODE == 1) rn *= QKSCALE;
        }
        #pragma unroll
        for (int nf = 0; nf < 4; ++nf){
          int col = n0 + wc * 64 + nf * 16 + (l & 15);
          float v = acc[mf][nf][r];
          if (MODE == 4){
            ((float*)outp)[row * 1024 + col] = v;
          } else if (MODE == 3){
            float g = v + bg[col];
            ((unsigned short*)outp)[row * 1024 + col] = f2h(1.f / (1.f + __expf(-g)));
          } else {
            int bb = row >> 10, ii = row & 1023;
            int d = nf * 16 + (l & 15);
            if (MODE == 1)
              ((unsigned short*)outp)[((bb * H_ + hcol) * N_ + ii) * DH_ + d] = f2h(v * rn);
            else
              ((unsigned short*)outp)[((bb * H_ + hcol) * J_ + NM_ + ii) * DH_ + d] = f2h(v * rn);
          }
        }
      }
    }
  }
}

// ---------------- fused attention: one workgroup per (b, i), big rows first ----------------
__global__ __launch_bounds__(256) void k_attn(
  const unsigned short* __restrict__ qn, const unsigned int* __restrict__ ktp,
  const unsigned int* __restrict__ vp, const float* __restrict__ wpre,
  const float* __restrict__ wpost, const float* __restrict__ hsc,
  const unsigned short* __restrict__ gate, unsigned short* __restrict__ aout)
{
  __shared__ unsigned short sd16[16][J_];   // f16: raw->mixed dots -> attn (in place)

  const int blk = blockIdx.x;
  const int b = blk & 3;
  const int i = 1023 - (blk >> 2);       // big rows dispatched first
  const int nA = i + 5;
  const int t = threadIdx.x;
  const unsigned int* qb32 = (const unsigned int*)qn;

  // ---- dots (fdot2 over d-pairs) + W_pre mix in registers ----
  for (int jb0 = 0; jb0 < nA; jb0 += 256){
    int j = jb0 + t;
    if (j < nA){
      int jblk = j >> 5, jj = j & 31;
      float a[16];
      for (int g = 0; g < 16; ++g){
        const unsigned int* qrow = qb32 + ((size_t)((b * 16 + g) * 1024 + i)) * 32;  // uniform -> s_load
        const unsigned int* kb = ktp + ((size_t)(b * 16 + g) * JB_ + jblk) * 1024 + jj;
        float s = 0.f;
        #pragma unroll
        for (int dp = 0; dp < 32; ++dp)
          s = fdot2(qrow[dp], kb[dp * 32], s);   // all offsets immediate (dp*128B < 4KB)
        a[g] = s;
      }
      #pragma unroll
      for (int h = 0; h < 16; ++h){
        float m = 0.f;
        #pragma unroll
        for (int g = 0; g < 16; ++g) m += wpre[h * 16 + g] * a[g];
        sd16[h][j] = f2h(m);
      }
    }
  }
  __syncthreads();

  // ---- per-head top-64 threshold + softmax (one wave per head-row, f16 keys) ----
  const int w = t >> 6, lane = t & 63;
  for (int h = w; h < 16; h += 4){
    float v[17]; unsigned int key[17];
    #pragma unroll
    for (int r = 0; r < 17; ++r){
      int j = lane + 64 * r;
      if (j < nA){
        unsigned int u = sd16[h][j];
        key[r] = (u & 0x8000u) ? (~u & 0xFFFFu) : (u | 0x8000u);
        v[r] = h2f((unsigned short)u);
      } else { key[r] = 0u; v[r] = -3.0e38f; }
    }
    float mx = v[0];
    #pragma unroll
    for (int r = 1; r < 17; ++r) mx = fmaxf(mx, v[r]);
    #pragma unroll
    for (int off = 32; off; off >>= 1) mx = fmaxf(mx, __shfl_xor(mx, off));

    unsigned int T = 0u;
    if (nA > TOPK_){
      for (int bit = 15; bit >= 2; --bit){
        unsigned int Tc = T | (1u << bit);
        int c = 0;
        #pragma unroll
        for (int r = 0; r < 17; ++r)
          c += __popcll(__ballot(key[r] >= Tc));
        if (c >= TOPK_) T = Tc;
      }
    }
    float s = 0.f;
    #pragma unroll
    for (int r = 0; r < 17; ++r){
      int j = lane + 64 * r;
      float e = (j < nA && key[r] >= T) ? __expf(v[r] - mx) : 0.f;
      v[r] = e; s += e;
    }
    #pragma unroll
    for (int off = 32; off; off >>= 1) s += __shfl_xor(s, off);
    float inv = 1.f / s;
    #pragma unroll
    for (int r = 0; r < 17; ++r){
      int j = lane + 64 * r;
      if (j < J_) sd16[h][j] = f2h(v[r] * inv);
    }
  }
  __syncthreads();

  // ---- W_post mix, per column (in place) ----
  for (int j = t; j < nA; j += 256){
    float a[16];
    #pragma unroll
    for (int g = 0; g < 16; ++g) a[g] = h2f(sd16[g][j]);
    #pragma unroll
    for (int h = 0; h < 16; ++h){
      float m = 0.f;
      #pragma unroll
      for (int g = 0; g < 16; ++g) m += wpost[h * 16 + g] * a[g];
      sd16[h][j] = f2h(m);
    }
  }
  __syncthreads();

  // ---- PV via fdot2 over j-pairs + head_scale + gate ----
  const int h = t >> 4, sg = t & 15, d0 = sg * 4;
  const int bg = b * 16 + h;
  const unsigned int* vb = vp + (size_t)bg * JP_ * 64 + d0;
  const unsigned int* ap = (const unsigned int*)&sd16[h][0];
  float acc[4] = {0.f, 0.f, 0.f, 0.f};
  const int npair = (nA + 1) >> 1;
  for (int jp = 0; jp < npair; ++jp){
    unsigned int a2 = ap[jp];                       // LDS broadcast within 16-lane group
    u32x4 vv = *(const u32x4*)(vb + (size_t)jp * 64);
    acc[0] = fdot2(vv[0], a2, acc[0]);
    acc[1] = fdot2(vv[1], a2, acc[1]);
    acc[2] = fdot2(vv[2], a2, acc[2]);
    acc[3] = fdot2(vv[3], a2, acc[3]);
  }
  float hs = hsc[h];
  const int row = (b << 10) | i;
  #pragma unroll
  for (int r = 0; r < 4; ++r){
    float g = h2f(gate[(size_t)row * 1024 + h * 64 + d0 + r]);
    aout[(size_t)row * 1024 + h * 64 + d0 + r] = f2b(acc[r] * hs * g);
  }
}

// ---------------- host ----------------
extern "C" void kernel_launch(void* const* d_in, const int* in_sizes, int n_in,
                              void* d_out, int out_size, void* d_ws, size_t ws_size,
                              hipStream_t stream) {
  const float* x     = (const float*)d_in[0];
  const float* Wq    = (const float*)d_in[1];
  const float* Wk    = (const float*)d_in[2];
  const float* Wv    = (const float*)d_in[3];
  const float* Wpre  = (const float*)d_in[4];
  const float* Wpost = (const float*)d_in[5];
  const float* mk    = (const float*)d_in[6];
  const float* mv    = (const float*)d_in[7];
  const float* hsc   = (const float*)d_in[8];
  const float* Wg    = (const float*)d_in[9];
  const float* bg    = (const float*)d_in[10];
  const float* Wo    = (const float*)d_in[11];
  float* out = (float*)d_out;

  char* ws = (char*)d_ws;
  size_t off = 0;
  auto alloc = [&](size_t bytes) -> void* {
    void* p = ws + off; off += (bytes + 255) & ~(size_t)255; return p;
  };
  unsigned short* xb   = (unsigned short*)alloc((size_t)4096 * 1024 * 2);
  unsigned short* wqb  = (unsigned short*)alloc((size_t)1024 * 1024 * 2);
  unsigned short* wkb  = (unsigned short*)alloc((size_t)1024 * 1024 * 2);
  unsigned short* wvb  = (unsigned short*)alloc((size_t)1024 * 1024 * 2);
  unsigned short* wgb  = (unsigned short*)alloc((size_t)1024 * 1024 * 2);
  unsigned short* wob  = (unsigned short*)alloc((size_t)1024 * 1024 * 2);
  unsigned short* qn   = (unsigned short*)alloc((size_t)B_ * H_ * N_ * DH_ * 2);   // f16
  unsigned short* kn   = (unsigned short*)alloc((size_t)B_ * H_ * J_ * DH_ * 2);   // f16
  unsigned short* gate = (unsigned short*)alloc((size_t)4096 * 1024 * 2);          // f16
  unsigned short* aout = (unsigned short*)alloc((size_t)4096 * 1024 * 2);          // bf16
  unsigned int*   ktp  = (unsigned int*)alloc((size_t)B_ * H_ * JB_ * 32 * 32 * 4);
  unsigned int*   vp   = (unsigned int*)alloc((size_t)B_ * H_ * JP_ * 64 * 4);

  k_cvt<<<1024, 256, 0, stream>>>(x,  xb,  4096 * 1024);
  k_cvt<<<512,  256, 0, stream>>>(Wq, wqb, 1024 * 1024);
  k_cvt<<<512,  256, 0, stream>>>(Wk, wkb, 1024 * 1024);
  k_cvt<<<512,  256, 0, stream>>>(Wv, wvb, 1024 * 1024);
  k_cvt<<<512,  256, 0, stream>>>(Wg, wgb, 1024 * 1024);
  k_cvt<<<512,  256, 0, stream>>>(Wo, wob, 1024 * 1024);

  k_mem<<<4, 256, 0, stream>>>(mk, mv, kn, vp);

  dim3 gg(8, 32);
  k_gemm<0><<<gg, 256, 0, stream>>>(xb, wvb, vp,   nullptr);
  k_gemm<1><<<gg, 256, 0, stream>>>(xb, wqb, qn,   nullptr);
  k_gemm<2><<<gg, 256, 0, stream>>>(xb, wkb, kn,   nullptr);
  k_gemm<3><<<gg, 256, 0, stream>>>(xb, wgb, gate, bg);

  k_tr<<<dim3(JB_, B_ * H_), 256, 0, stream>>>(kn, ktp);

  k_attn<<<4096, 256, 0, stream>>>(qn, ktp, vp, Wpre, Wpost, hsc, gate, aout);

  k_gemm<4><<<gg, 256, 0, stream>>>(aout, wob, out, nullptr);
}